// Round 1
// baseline (815.526 us; speedup 1.0000x reference)
//
#include <hip/hip_runtime.h>
#include <cstddef>

#define BB 128
#define DD 100

// ---------------------------------------------------------------------------
// Kernel 1: per-sample forward. z = x@W1^T + b1 ; h = gelu(z) ;
// out = h@W2^T + b2. Also writes g1 = gelu'(z), g2 = gelu''(z) to workspace.
// One block per sample, 128 threads (100 active).
// ---------------------------------------------------------------------------
__global__ __launch_bounds__(128) void k_fwd(
    const float* __restrict__ x, const float* __restrict__ W1,
    const float* __restrict__ b1, const float* __restrict__ W2,
    const float* __restrict__ b2, float* __restrict__ out,
    float* __restrict__ g1, float* __restrict__ g2)
{
    const int i = blockIdx.x;
    const int t = threadIdx.x;
    __shared__ float xs[DD];
    __shared__ float hs[DD];
    if (t < DD) xs[t] = x[i * DD + t];
    __syncthreads();
    if (t < DD) {
        float z = b1[t];
        const float* w = W1 + t * DD;
        for (int k = 0; k < DD; ++k) z = fmaf(xs[k], w[k], z);
        const float cdf = 0.5f * (1.0f + erff(z * 0.7071067811865476f));
        const float pdf = 0.3989422804014327f * expf(-0.5f * z * z);
        hs[t] = z * cdf;                    // gelu(z)
        g1[i * DD + t] = cdf + z * pdf;     // gelu'(z)
        g2[i * DD + t] = (2.0f - z * z) * pdf; // gelu''(z)
    }
    __syncthreads();
    if (t < DD) {
        float acc = b2[t];
        const float* w = W2 + t * DD;
        for (int j = 0; j < DD; ++j) acc = fmaf(hs[j], w[j], acc);
        out[i * DD + t] = acc;
    }
}

// ---------------------------------------------------------------------------
// Kernel 2: Jacobian. jac[i,o,k] = sum_j W2[o,j]*g1[i,j]*W1[j,k].
// One block per sample. Stage A[o,j] = W2[o,j]*g1[i,j] in LDS (40 KB),
// stream W1 rows from L1 (40 KB, hot). 250 active threads, each computes a
// 10(o) x 4(k) register tile with K=100.
// ---------------------------------------------------------------------------
__global__ __launch_bounds__(256) void k_jac(
    const float* __restrict__ W1, const float* __restrict__ W2,
    const float* __restrict__ g1, float* __restrict__ jac)
{
    const int i = blockIdx.x;
    const int t = threadIdx.x;
    __shared__ float As[DD * DD];
    __shared__ float gs[DD];
    if (t < DD) gs[t] = g1[i * DD + t];
    __syncthreads();
    for (int idx = t; idx < DD * DD; idx += 256)
        As[idx] = W2[idx] * gs[idx % DD];
    __syncthreads();
    if (t < 250) {
        const int k0 = (t % 25) * 4;
        const int o0 = (t / 25) * 10;
        float acc[10][4];
#pragma unroll
        for (int o = 0; o < 10; ++o)
#pragma unroll
            for (int c = 0; c < 4; ++c) acc[o][c] = 0.0f;
        for (int j = 0; j < DD; ++j) {
            const float4 w = *(const float4*)(W1 + j * DD + k0);
#pragma unroll
            for (int o = 0; o < 10; ++o) {
                const float a = As[(o0 + o) * DD + j];
                acc[o][0] = fmaf(a, w.x, acc[o][0]);
                acc[o][1] = fmaf(a, w.y, acc[o][1]);
                acc[o][2] = fmaf(a, w.z, acc[o][2]);
                acc[o][3] = fmaf(a, w.w, acc[o][3]);
            }
        }
#pragma unroll
        for (int o = 0; o < 10; ++o) {
            float4 v = make_float4(acc[o][0], acc[o][1], acc[o][2], acc[o][3]);
            *(float4*)(jac + ((size_t)i * DD + o0 + o) * DD + k0) = v;
        }
    }
}

// ---------------------------------------------------------------------------
// Kernel 3: Hessian. hess[i,o,k,l] = sum_j W2[o,j]*g2[i,j]*W1[j,k]*W1[j,l].
// One block per (i,k): 12800 blocks. Stage U[o,j] = W2[o,j]*g2[i,j]*W1[j,k]
// in LDS (40 KB -> 3 blocks/CU); stream W1[j,l0:4] from L1. Each of 250
// threads computes a 10(o) x 4(l) register tile, K=100 -> 4000 FMA/thread.
// ---------------------------------------------------------------------------
__global__ __launch_bounds__(256) void k_hess(
    const float* __restrict__ W1, const float* __restrict__ W2,
    const float* __restrict__ g2, float* __restrict__ hess)
{
    const int k = blockIdx.x;
    const int i = blockIdx.y;
    const int t = threadIdx.x;
    __shared__ float Us[DD * DD];
    __shared__ float sj[DD];
    if (t < DD) sj[t] = g2[i * DD + t] * W1[t * DD + k];
    __syncthreads();
    for (int idx = t; idx < DD * DD; idx += 256)
        Us[idx] = W2[idx] * sj[idx % DD];
    __syncthreads();
    if (t < 250) {
        const int l0 = (t % 25) * 4;
        const int o0 = (t / 25) * 10;
        float acc[10][4];
#pragma unroll
        for (int o = 0; o < 10; ++o)
#pragma unroll
            for (int c = 0; c < 4; ++c) acc[o][c] = 0.0f;
        for (int j = 0; j < DD; ++j) {
            const float4 w = *(const float4*)(W1 + j * DD + l0);
#pragma unroll
            for (int o = 0; o < 10; ++o) {
                const float a = Us[(o0 + o) * DD + j];
                acc[o][0] = fmaf(a, w.x, acc[o][0]);
                acc[o][1] = fmaf(a, w.y, acc[o][1]);
                acc[o][2] = fmaf(a, w.z, acc[o][2]);
                acc[o][3] = fmaf(a, w.w, acc[o][3]);
            }
        }
#pragma unroll
        for (int o = 0; o < 10; ++o) {
            const size_t off = (((size_t)i * DD + o0 + o) * DD + k) * DD + l0;
            float4 v = make_float4(acc[o][0], acc[o][1], acc[o][2], acc[o][3]);
            *(float4*)(hess + off) = v;
        }
    }
}

extern "C" void kernel_launch(void* const* d_in, const int* in_sizes, int n_in,
                              void* d_out, int out_size, void* d_ws, size_t ws_size,
                              hipStream_t stream)
{
    const float* x  = (const float*)d_in[0];
    const float* W1 = (const float*)d_in[1];
    const float* b1 = (const float*)d_in[2];
    const float* W2 = (const float*)d_in[3];
    const float* b2 = (const float*)d_in[4];

    float* out  = (float*)d_out;                       // (128,100)
    float* jac  = out + (size_t)BB * DD;               // (128,100,100)
    float* hess = jac + (size_t)BB * DD * DD;          // (128,100,100,100)

    float* g1 = (float*)d_ws;                          // (128,100)
    float* g2 = g1 + (size_t)BB * DD;                  // (128,100)

    k_fwd<<<BB, 128, 0, stream>>>(x, W1, b1, W2, b2, out, g1, g2);
    k_jac<<<BB, 256, 0, stream>>>(W1, W2, g1, jac);
    k_hess<<<dim3(DD, BB), 256, 0, stream>>>(W1, W2, g2, hess);
}